// Round 5
// baseline (310.946 us; speedup 1.0000x reference)
//
#include <hip/hip_runtime.h>

// PulseRetrievalLossFunction: B=4096, N=8192 fp32; H=N/2 per half.
// loss = mean_rows( mean_H(w*(p-l)^2)_real + mean_H(w*(p-l)^2)_imag )
// w = PENALTY outside [first,last] significant (|lab|>THR) index span, else 1.
//
// R5: stage1 streams 268.4 MB at ~6.2 TB/s (= read roofline; NT/L3 tricks
// proved null in R4). Remaining cost is the stage2 tail (~4 us of graph-node
// latency + tiny kernel). Fuse it: last-block-done pattern with a device-scope
// counter. Counter zeroed per call via 4-byte hipMemsetAsync (graph-legal).

#define HALF_N 4096
#define PENALTY 2.0f
#define THR 0.01f

typedef __attribute__((ext_vector_type(4))) float f32x4;

__global__ __launch_bounds__(256) void prl_fused(const float* __restrict__ pred,
                                                 const float* __restrict__ lab,
                                                 float* __restrict__ partial,
                                                 unsigned int* __restrict__ cnt,
                                                 float* __restrict__ out,
                                                 int rowStride,   // N = 8192
                                                 int nsegs,       // 2*B
                                                 float scale) {   // 1/(B*H)
    const int seg  = blockIdx.x;
    const int half = seg & 1;
    const int row  = seg >> 1;
    const long long base = (long long)row * rowStride + (long long)half * HALF_N;
    const f32x4* __restrict__ p4 = reinterpret_cast<const f32x4*>(pred + base);
    const f32x4* __restrict__ l4 = reinterpret_cast<const f32x4*>(lab + base);
    const int t = threadIdx.x;

    // Each thread: 4 strided float4 loads per array -> 16 elements, sq in regs.
    float sq[4][4];
    int minIdx = HALF_N;   // H if no significant element
    int maxIdx = -1;

    #pragma unroll
    for (int k = 0; k < 4; ++k) {
        const int vi = t + k * 256;           // float4 index in [0,1024)
        const f32x4 lv = l4[vi];
        const f32x4 pv = p4[vi];
        #pragma unroll
        for (int c = 0; c < 4; ++c) {
            const float d = pv[c] - lv[c];
            sq[k][c] = d * d;
            if (fabsf(lv[c]) > THR) {
                const int idx = vi * 4 + c;
                minIdx = min(minIdx, idx);
                maxIdx = max(maxIdx, idx);
            }
        }
    }

    // Wave (64-lane) reduce min/max.
    #pragma unroll
    for (int off = 32; off > 0; off >>= 1) {
        minIdx = min(minIdx, __shfl_down(minIdx, off, 64));
        maxIdx = max(maxIdx, __shfl_down(maxIdx, off, 64));
    }
    __shared__ int smin[4], smax[4];
    const int wave = t >> 6;
    if ((t & 63) == 0) { smin[wave] = minIdx; smax[wave] = maxIdx; }
    __syncthreads();
    int first = min(min(smin[0], smin[1]), min(smin[2], smin[3]));
    int last  = max(max(smax[0], smax[1]), max(smax[2], smax[3]));
    if (first == HALF_N) first = 0;      // all-insignificant fallback
    if (last < 0)        last = HALF_N - 1;

    // Weighted sum from registers (no re-read of memory).
    float sum = 0.0f;
    #pragma unroll
    for (int k = 0; k < 4; ++k) {
        const int vi = t + k * 256;
        #pragma unroll
        for (int c = 0; c < 4; ++c) {
            const int idx = vi * 4 + c;
            const float w = (idx < first || idx > last) ? PENALTY : 1.0f;
            sum += w * sq[k][c];
        }
    }
    #pragma unroll
    for (int off = 32; off > 0; off >>= 1)
        sum += __shfl_down(sum, off, 64);
    __shared__ float ssum[4];
    if ((t & 63) == 0) ssum[wave] = sum;
    __syncthreads();

    // Publish partial, count completions (ACQ_REL agent scope = release our
    // partial store, acquire-invalidate stale lines for the winner).
    __shared__ int amLast;
    if (t == 0) {
        partial[seg] = ssum[0] + ssum[1] + ssum[2] + ssum[3];
        const unsigned int old =
            __hip_atomic_fetch_add(cnt, 1u, __ATOMIC_ACQ_REL, __HIP_MEMORY_SCOPE_AGENT);
        amLast = (old == (unsigned int)(nsegs - 1));
    }
    __syncthreads();

    if (amLast) {
        float s = 0.0f;
        const f32x4* __restrict__ pp = reinterpret_cast<const f32x4*>(partial);
        for (int i = t; i < nsegs / 4; i += 256) {
            const f32x4 v = pp[i];
            s += (v[0] + v[1]) + (v[2] + v[3]);
        }
        #pragma unroll
        for (int off = 32; off > 0; off >>= 1)
            s += __shfl_down(s, off, 64);
        __shared__ float fsum[4];
        if ((t & 63) == 0) fsum[wave] = s;
        __syncthreads();
        if (t == 0)
            out[0] = (fsum[0] + fsum[1] + fsum[2] + fsum[3]) * scale;
    }
}

extern "C" void kernel_launch(void* const* d_in, const int* in_sizes, int n_in,
                              void* d_out, int out_size, void* d_ws, size_t ws_size,
                              hipStream_t stream) {
    const float* pred = (const float*)d_in[0];
    const float* lab  = (const float*)d_in[1];
    float* out = (float*)d_out;

    const int N = 8192;                  // per reference setup
    const int total = in_sizes[0];
    const int B = total / N;             // 4096
    const int nsegs = 2 * B;             // 8192
    const float scale = 1.0f / ((float)B * (float)HALF_N);

    float* partial = (float*)d_ws;                         // nsegs floats
    unsigned int* cnt = (unsigned int*)((char*)d_ws + (size_t)nsegs * sizeof(float));

    hipMemsetAsync(cnt, 0, sizeof(unsigned int), stream);  // graph-capturable
    prl_fused<<<nsegs, 256, 0, stream>>>(pred, lab, partial, cnt, out, N, nsegs, scale);
}

// Round 6
// 46.791 us; speedup vs baseline: 6.6454x; 6.6454x over previous
//
#include <hip/hip_runtime.h>

// PulseRetrievalLossFunction: B=4096, N=8192 fp32; H=N/2 per half.
// loss = mean_rows( mean_H(w*(p-l)^2)_real + mean_H(w*(p-l)^2)_imag )
// w = PENALTY outside [first,last] significant (|lab|>THR) index span, else 1.
//
// R6: REVERT to R3 (best: 47.3us, stage1 at ~97% of measured 6.29 TB/s read
// ceiling). R4 (nt loads for L3 partitioning) was neutral; R5 (fused tail via
// agent-scope ACQ_REL counter) regressed 6.5x — each ACQ_REL RMW on gfx950
// emits buffer_wbl2+buffer_inv (non-coherent per-XCD L2), 8192 of them killed
// all caching. Two-kernel structure is the roofline shape for this op.

#define HALF_N 4096
#define PENALTY 2.0f
#define THR 0.01f
#define NSEG 8192          // 2 * B segments

__global__ __launch_bounds__(256) void prl_stage1(const float* __restrict__ pred,
                                                  const float* __restrict__ lab,
                                                  float* __restrict__ partial,
                                                  int rowStride) {  // N = 8192
    const int half = blockIdx.x & 1;
    const int row  = blockIdx.x >> 1;
    const long long base = (long long)row * rowStride + (long long)half * HALF_N;
    const float4* __restrict__ p4 = reinterpret_cast<const float4*>(pred + base);
    const float4* __restrict__ l4 = reinterpret_cast<const float4*>(lab + base);
    const int t = threadIdx.x;

    // Each thread: 4 strided float4 loads per array -> 16 elements, sq in regs.
    float sq[4][4];
    int minIdx = HALF_N;   // H if no significant element
    int maxIdx = -1;

    #pragma unroll
    for (int k = 0; k < 4; ++k) {
        const int vi = t + k * 256;           // float4 index in [0,1024)
        const float4 lv = l4[vi];
        const float4 pv = p4[vi];
        const float ls[4] = {lv.x, lv.y, lv.z, lv.w};
        const float ps[4] = {pv.x, pv.y, pv.z, pv.w};
        #pragma unroll
        for (int c = 0; c < 4; ++c) {
            const float d = ps[c] - ls[c];
            sq[k][c] = d * d;
            if (fabsf(ls[c]) > THR) {
                const int idx = vi * 4 + c;
                minIdx = min(minIdx, idx);
                maxIdx = max(maxIdx, idx);
            }
        }
    }

    // Wave (64-lane) reduce min/max.
    #pragma unroll
    for (int off = 32; off > 0; off >>= 1) {
        minIdx = min(minIdx, __shfl_down(minIdx, off, 64));
        maxIdx = max(maxIdx, __shfl_down(maxIdx, off, 64));
    }
    __shared__ int smin[4], smax[4];
    const int wave = t >> 6;
    if ((t & 63) == 0) { smin[wave] = minIdx; smax[wave] = maxIdx; }
    __syncthreads();
    int first = min(min(smin[0], smin[1]), min(smin[2], smin[3]));
    int last  = max(max(smax[0], smax[1]), max(smax[2], smax[3]));
    if (first == HALF_N) first = 0;      // all-insignificant fallback
    if (last < 0)        last = HALF_N - 1;

    // Weighted sum from registers (no re-read of HBM).
    float sum = 0.0f;
    #pragma unroll
    for (int k = 0; k < 4; ++k) {
        const int vi = t + k * 256;
        #pragma unroll
        for (int c = 0; c < 4; ++c) {
            const int idx = vi * 4 + c;
            const float w = (idx < first || idx > last) ? PENALTY : 1.0f;
            sum += w * sq[k][c];
        }
    }
    #pragma unroll
    for (int off = 32; off > 0; off >>= 1)
        sum += __shfl_down(sum, off, 64);
    __shared__ float ssum[4];
    if ((t & 63) == 0) ssum[wave] = sum;
    __syncthreads();
    if (t == 0)
        partial[blockIdx.x] = ssum[0] + ssum[1] + ssum[2] + ssum[3];
}

__global__ __launch_bounds__(1024) void prl_stage2(const float* __restrict__ partial,
                                                   float* __restrict__ out,
                                                   float scale) {
    const int t = threadIdx.x;
    float s = 0.0f;
    #pragma unroll
    for (int k = 0; k < NSEG / 1024; ++k)
        s += partial[t + k * 1024];
    #pragma unroll
    for (int off = 32; off > 0; off >>= 1)
        s += __shfl_down(s, off, 64);
    __shared__ float ws[16];
    if ((t & 63) == 0) ws[t >> 6] = s;
    __syncthreads();
    if (t == 0) {
        float tot = 0.0f;
        #pragma unroll
        for (int i = 0; i < 16; ++i) tot += ws[i];
        out[0] = tot * scale;
    }
}

extern "C" void kernel_launch(void* const* d_in, const int* in_sizes, int n_in,
                              void* d_out, int out_size, void* d_ws, size_t ws_size,
                              hipStream_t stream) {
    const float* pred = (const float*)d_in[0];
    const float* lab  = (const float*)d_in[1];
    float* out = (float*)d_out;
    float* partial = (float*)d_ws;       // NSEG floats = 32 KB

    const int N = 8192;                  // per reference setup
    const int total = in_sizes[0];
    const int B = total / N;             // 4096
    const float scale = 1.0f / ((float)B * (float)HALF_N);

    prl_stage1<<<2 * B, 256, 0, stream>>>(pred, lab, partial, N);
    prl_stage2<<<1, 1024, 0, stream>>>(partial, out, scale);
}